// Round 2
// baseline (169.067 us; speedup 1.0000x reference)
//
#include <hip/hip_runtime.h>
#include <cmath>

// Problem constants
#define BATCH 8
#define NH 8
#define SEQ 1024
#define DH 64          // head dim
#define NM 64          // modes

// ws layout (floats):
//  Pr2 : [th 2][inp 2][bh 64][c 2][m 64][d 64] = 2,097,152  (2 t-partials)
//  C2  : [bh 64][j 64][m 64][c 2]              =   524,288
#define PLANE 4096     // 64m * 64d
#define C2_OFF (4 * 64 * 2 * PLANE)   // 2,097,152 floats

// ---------------------------------------------------------------------------
// Kernel 1: forward partial DFT with t<->t+512 symmetry, 2 t-partials only.
// grid = (bh 64, inp 2, dh 2, th 2) = 512 blocks x 512 thr.
// LDS 72 KB -> 2 blocks/CU = 16 waves/CU = 4 waves/SIMD.
// Thread: 2 modes (one parity) x 8 d, 4-way t-interleave (shfl_xor 4,8).
// Eliminates the old 33.5 MB 8-partial buffer + the k_red dispatch.
// ---------------------------------------------------------------------------
__global__ __launch_bounds__(512, 4) void k_dft(const float* __restrict__ q,
                                                const float* __restrict__ k,
                                                float* __restrict__ Pr) {
  const int bid = blockIdx.x;
  const int bh = bid & 63;
  const int inp = (bid >> 6) & 1;
  const int dh = (bid >> 7) & 1;   // which 32-d half
  const int th = bid >> 8;         // which 256-t' half
  const float* x = (inp ? k : q) + (size_t)bh * (SEQ * DH);  // [t][d]

  __shared__ __align__(16) float se[256 * 36];  // row stride 36 (9 quads, odd)
  __shared__ __align__(16) float so[256 * 36];
  const int tid = threadIdx.x;
  const int dg  = tid & 3;         // 4 d-groups of 8 -> d0 in [0,32)
  const int par = (tid >> 2) & 3;  // 4-way t-interleave stream
  const int pg  = (tid >> 4) & 1;  // mode parity
  const int mgl = tid >> 5;        // 0..15 -> 2 modes each
  const int d0 = dg * 8;
  // modes handled: m = 4*mgl + 2*mi + pg, mi in {0,1}

  const int tb = th * 256;
  {
    const float4* xf = reinterpret_cast<const float4*>(x);
#pragma unroll
    for (int i = 0; i < 4; ++i) {
      int idx = tid + i * 512;          // 0..2047
      int tt = idx >> 3, f4 = idx & 7;  // t'-row, float4 within 32-float half
      size_t ga = (size_t)(tb + tt) * 16 + dh * 8 + f4;
      float4 a = xf[ga];
      float4 b = xf[ga + 512 * 16];
      *reinterpret_cast<float4*>(&se[tt * 36 + f4 * 4]) =
          make_float4(a.x + b.x, a.y + b.y, a.z + b.z, a.w + b.w);
      *reinterpret_cast<float4*>(&so[tt * 36 + f4 * 4]) =
          make_float4(a.x - b.x, a.y - b.y, a.z - b.z, a.w - b.w);
    }
  }
  __syncthreads();

  const float* s = pg ? so : se;

  float accr[2][8] = {{0.f}}, acci[2][8] = {{0.f}};
  float stepc[2], steps[2], wr[2], wi[2];
#pragma unroll
  for (int mi = 0; mi < 2; ++mi) {
    const int m = 4 * mgl + 2 * mi + pg;
    const int ps = (4 * m) & 1023;  // t' advances by 4
    stepc[mi] = cospif((float)ps * (1.0f / 512.0f));
    steps[mi] = -sinpif((float)ps * (1.0f / 512.0f));
    const int p0 = (m * (tb + par)) & 1023;
    wr[mi] = cospif((float)p0 * (1.0f / 512.0f));
    wi[mi] = -sinpif((float)p0 * (1.0f / 512.0f));
  }

#pragma unroll 4
  for (int k2 = 0; k2 < 64; ++k2) {
    const int tl = 4 * k2 + par;
    float4 a = *reinterpret_cast<const float4*>(&s[tl * 36 + d0]);
    float4 b = *reinterpret_cast<const float4*>(&s[tl * 36 + d0 + 4]);
    float xv[8] = {a.x, a.y, a.z, a.w, b.x, b.y, b.z, b.w};
#pragma unroll
    for (int mi = 0; mi < 2; ++mi) {
      float cwr = wr[mi], cwi = wi[mi];
#pragma unroll
      for (int di = 0; di < 8; ++di) {
        accr[mi][di] = fmaf(cwr, xv[di], accr[mi][di]);
        acci[mi][di] = fmaf(cwi, xv[di], acci[mi][di]);
      }
      float nr = cwr * stepc[mi] - cwi * steps[mi];
      float ni = cwr * steps[mi] + cwi * stepc[mi];
      wr[mi] = nr; wi[mi] = ni;
    }
  }

  // combine 4 par streams (partner lanes differ in bits 2,3)
#pragma unroll
  for (int mi = 0; mi < 2; ++mi) {
#pragma unroll
    for (int di = 0; di < 8; ++di) {
      accr[mi][di] += __shfl_xor(accr[mi][di], 4, 64);
      acci[mi][di] += __shfl_xor(acci[mi][di], 4, 64);
      accr[mi][di] += __shfl_xor(accr[mi][di], 8, 64);
      acci[mi][di] += __shfl_xor(acci[mi][di], 8, 64);
    }
  }

  if (par == 0) {
    const size_t base =
        (((size_t)th * 2 + inp) * 64 + bh) * (2 * PLANE) + dh * 32 + d0;
#pragma unroll
    for (int mi = 0; mi < 2; ++mi) {
      const int m = 4 * mgl + 2 * mi + pg;
      float* pr = Pr + base + (size_t)m * 64;
      float* pi = pr + PLANE;
      *reinterpret_cast<float4*>(pr) =
          make_float4(accr[mi][0], accr[mi][1], accr[mi][2], accr[mi][3]);
      *reinterpret_cast<float4*>(pr + 4) =
          make_float4(accr[mi][4], accr[mi][5], accr[mi][6], accr[mi][7]);
      *reinterpret_cast<float4*>(pi) =
          make_float4(acci[mi][0], acci[mi][1], acci[mi][2], acci[mi][3]);
      *reinterpret_cast<float4*>(pi + 4) =
          make_float4(acci[mi][4], acci[mi][5], acci[mi][6], acci[mi][7]);
    }
  }
}

// stable complex tanh
__device__ __forceinline__ void ctanh_f(float x, float y, float& rr, float& ri) {
  float a = 2.0f * x, b = 2.0f * y;
  if (fabsf(a) > 20.0f) {
    rr = (a > 0.0f) ? 1.0f : -1.0f;
    ri = 0.0f;
  } else {
    float ea = expf(a), ena = expf(-a);
    float sb, cb;
    sincosf(b, &sb, &cb);
    float den = 0.5f * (ea + ena) + cb;
    rr = 0.5f * (ea - ena) / den;
    ri = sb / den;
  }
}

// ---------------------------------------------------------------------------
// Kernel 2: fused mid stage. grid = (bh, q-eighth) = 512 blocks x 512 thr,
// ~47 KB LDS -> 3 blocks/CU. Stages K/Q (summing the 2 t-partials inline),
// scores -> ctanh -> context (C1 in LDS) -> C2 = C1 x w, written directly.
// Removes the C1c global round-trip and the separate k_mid_b dispatch.
// ---------------------------------------------------------------------------
__global__ __launch_bounds__(512) void k_mid(const float* __restrict__ Pr,
                                             const float* __restrict__ wre,
                                             const float* __restrict__ wim,
                                             float* __restrict__ C2) {
  __shared__ float Kr[64][68], Ki[64][68];
  __shared__ float Qr[8][68], Qi[8][68];
  __shared__ float Ar[8][68], Ai[8][68];
  __shared__ float C1rs[64][9], C1is[64][9];

  const int tid = threadIdx.x;
  const int bh = blockIdx.x >> 3;
  const int qo = blockIdx.x & 7;  // 8 q's per block

  const float4* pf = reinterpret_cast<const float4*>(Pr);
  const size_t TH4 = (size_t)2 * 64 * 2 * 1024;  // th stride in float4 = 262144

  // K: Pr[th][inp=1][bh][c][m][d], sum th partials
  const float4* k0 = pf + (size_t)(64 + bh) * 2048;
  const float4* k1 = k0 + TH4;
  for (int idx = tid; idx < 1024; idx += 512) {
    int kk = idx >> 4, dd = (idx & 15) * 4;
    float4 r0 = k0[idx], r1 = k1[idx];
    float4 i0 = k0[idx + 1024], i1 = k1[idx + 1024];
    *reinterpret_cast<float4*>(&Kr[kk][dd]) =
        make_float4(r0.x + r1.x, r0.y + r1.y, r0.z + r1.z, r0.w + r1.w);
    *reinterpret_cast<float4*>(&Ki[kk][dd]) =
        make_float4(i0.x + i1.x, i0.y + i1.y, i0.z + i1.z, i0.w + i1.w);
  }
  // Q: Pr[th][inp=0][bh][c][qo*8 .. qo*8+7][d], sum th partials
  {
    const float4* q0 = pf + (size_t)bh * 2048 + qo * 128;
    const float4* q1 = q0 + TH4;
    if (tid < 128) {
      int qi2 = tid >> 4, dd = (tid & 15) * 4;
      float4 r0 = q0[tid], r1 = q1[tid];
      float4 i0 = q0[tid + 1024], i1 = q1[tid + 1024];
      *reinterpret_cast<float4*>(&Qr[qi2][dd]) =
          make_float4(r0.x + r1.x, r0.y + r1.y, r0.z + r1.z, r0.w + r1.w);
      *reinterpret_cast<float4*>(&Qi[qi2][dd]) =
          make_float4(i0.x + i1.x, i0.y + i1.y, i0.z + i1.z, i0.w + i1.w);
    }
  }
  __syncthreads();

  // scores S[q][k] = sum_d Q[q][d]*K[k][d] (complex, no conj) -> ctanh
  {
    const int qq = tid >> 6, kk = tid & 63;
    float s0 = 0.f, s1 = 0.f;
    for (int d = 0; d < 64; d += 4) {
      const float4 qr = *reinterpret_cast<const float4*>(&Qr[qq][d]);
      const float4 qi = *reinterpret_cast<const float4*>(&Qi[qq][d]);
      const float4 kr = *reinterpret_cast<const float4*>(&Kr[kk][d]);
      const float4 ki = *reinterpret_cast<const float4*>(&Ki[kk][d]);
      s0 = fmaf(qr.x, kr.x, s0); s0 = fmaf(-qi.x, ki.x, s0);
      s1 = fmaf(qr.x, ki.x, s1); s1 = fmaf(qi.x, kr.x, s1);
      s0 = fmaf(qr.y, kr.y, s0); s0 = fmaf(-qi.y, ki.y, s0);
      s1 = fmaf(qr.y, ki.y, s1); s1 = fmaf(qi.y, kr.y, s1);
      s0 = fmaf(qr.z, kr.z, s0); s0 = fmaf(-qi.z, ki.z, s0);
      s1 = fmaf(qr.z, ki.z, s1); s1 = fmaf(qi.z, kr.z, s1);
      s0 = fmaf(qr.w, kr.w, s0); s0 = fmaf(-qi.w, ki.w, s0);
      s1 = fmaf(qr.w, ki.w, s1); s1 = fmaf(qi.w, kr.w, s1);
    }
    float rr, ri;
    ctanh_f(s0, s1, rr, ri);
    Ar[qq][kk] = rr;
    Ai[qq][kk] = ri;
  }
  __syncthreads();

  // C1[d][q] = sum_k A[q][k]*K[k][d]; thread (q, d) -> lane-consecutive K
  {
    const int qq = tid >> 6, dd = tid & 63;
    float cr = 0.f, ci = 0.f;
#pragma unroll 8
    for (int kk = 0; kk < 64; ++kk) {
      float a_r = Ar[qq][kk], a_i = Ai[qq][kk];  // broadcast
      float krv = Kr[kk][dd], kiv = Ki[kk][dd];
      cr = fmaf(a_r, krv, cr); cr = fmaf(-a_i, kiv, cr);
      ci = fmaf(a_r, kiv, ci); ci = fmaf(a_i, krv, ci);
    }
    C1rs[dd][qq] = cr;
    C1is[dd][qq] = ci;
  }
  __syncthreads();

  // fused former k_mid_b: C2[j][q] = sum_i C1[i][q] * w[h][i][j][q]
  {
    const int j = tid >> 3, ql = tid & 7;
    const int h = bh & 7;
    const int qg = qo * 8 + ql;
    const float* wrp = wre + (size_t)h * 262144 + (size_t)j * 64 + qg;
    const float* wip = wim + (size_t)h * 262144 + (size_t)j * 64 + qg;
    float ar = 0.f, ai = 0.f;
#pragma unroll 8
    for (int i = 0; i < 64; ++i) {
      float wr = wrp[(size_t)i * 4096];
      float wi = wip[(size_t)i * 4096];
      float cr = C1rs[i][ql], cim = C1is[i][ql];
      ar = fmaf(cr, wr, ar); ar = fmaf(-cim, wi, ar);
      ai = fmaf(cr, wi, ai); ai = fmaf(cim, wr, ai);
    }
    *reinterpret_cast<float2*>(&C2[(((size_t)bh * 64 + j) * 64 + qg) * 2]) =
        make_float2(ar, ai);
  }
}

// ---------------------------------------------------------------------------
// Kernel 3 (unchanged, control): inverse partial DFT with (-1)^m symmetry.
// grid = (bh 64, tc 8, jh 2) = 1024 blocks x 256 thr. LDS 18.4 KB.
// ---------------------------------------------------------------------------
__global__ __launch_bounds__(256) void k_idft(const float* __restrict__ C2,
                                              float* __restrict__ out) {
  __shared__ float Cr[64][36], Ci[64][36];
  const int tid = threadIdx.x;
  const int jh = blockIdx.x & 1;
  const int tc = (blockIdx.x >> 1) & 7;
  const int bh = blockIdx.x >> 4;
  const float s = 1.0f / (512.0f * 512.0f * 1024.0f);

  // stage 64 m x 32 j (this block's j-half), scale pre-folded
  for (int idx = tid; idx < 2048; idx += 256) {
    int j = idx >> 6, m = idx & 63;  // j 0..31 local
    int jg_ = jh * 32 + j;
    float f = (m == 0) ? s : 2.0f * s;
    float2 c = *reinterpret_cast<const float2*>(&C2[(((size_t)bh * 64 + jg_) * 64 + m) * 2]);
    Cr[m][j] = f * c.x;
    Ci[m][j] = f * c.y;
  }
  __syncthreads();

  const int tg = tid & 15, jg = tid >> 4;  // tg 16 x 4t', jg 16 x 2j
  const int tp0 = tc * 64 + tg * 4;        // 4 consecutive t'
  const int j0 = jg * 2;                   // 2 consecutive j (local)

  float sc[4], ss[4], wc[4], wsn[4];
#pragma unroll
  for (int kk = 0; kk < 4; ++kk) {
    float ph = (float)((tp0 + kk) & 1023) * (1.0f / 512.0f);
    sc[kk] = cospif(ph);  // step e^{+2*pi*i*t'/1024} per m
    ss[kk] = sinpif(ph);
    wc[kk] = 1.0f;        // m = 0
    wsn[kk] = 0.0f;
  }

  float accE[4][2] = {{0.f}}, accO[4][2] = {{0.f}};
#pragma unroll 4
  for (int m = 0; m < 64; ++m) {
    float2 c0 = *reinterpret_cast<const float2*>(&Cr[m][j0]);
    float2 e0 = *reinterpret_cast<const float2*>(&Ci[m][j0]);
    float crv[2] = {c0.x, c0.y};
    float civ[2] = {e0.x, e0.y};
    float(*acc)[2] = (m & 1) ? accO : accE;
#pragma unroll
    for (int kk = 0; kk < 4; ++kk) {
      float cw = wc[kk], sw = wsn[kk];
#pragma unroll
      for (int jj = 0; jj < 2; ++jj) {
        acc[kk][jj] = fmaf(crv[jj], cw, acc[kk][jj]);
        acc[kk][jj] = fmaf(-civ[jj], sw, acc[kk][jj]);
      }
      float nr = cw * sc[kk] - sw * ss[kk];
      float ni = cw * ss[kk] + sw * sc[kk];
      wc[kk] = nr; wsn[kk] = ni;
    }
  }

  // out[bh][j][t]: float4 at tp0 (E+O) and float4 at tp0+512 (E-O)
#pragma unroll
  for (int jj = 0; jj < 2; ++jj) {
    float* row = &out[((size_t)bh * 64 + jh * 32 + j0 + jj) * 1024];
    *reinterpret_cast<float4*>(&row[tp0]) =
        make_float4(accE[0][jj] + accO[0][jj], accE[1][jj] + accO[1][jj],
                    accE[2][jj] + accO[2][jj], accE[3][jj] + accO[3][jj]);
    *reinterpret_cast<float4*>(&row[tp0 + 512]) =
        make_float4(accE[0][jj] - accO[0][jj], accE[1][jj] - accO[1][jj],
                    accE[2][jj] - accO[2][jj], accE[3][jj] - accO[3][jj]);
  }
}

extern "C" void kernel_launch(void* const* d_in, const int* in_sizes, int n_in,
                              void* d_out, int out_size, void* d_ws, size_t ws_size,
                              hipStream_t stream) {
  const float* q   = (const float*)d_in[0];
  const float* k   = (const float*)d_in[1];
  // d_in[2] = value, unused by the reference forward
  const float* wre = (const float*)d_in[3];
  const float* wim = (const float*)d_in[4];
  float* out = (float*)d_out;
  float* ws  = (float*)d_ws;

  float* Pr = ws;
  float* C2 = ws + C2_OFF;

  k_dft <<<512, 512, 0, stream>>>(q, k, Pr);
  k_mid <<<512, 512, 0, stream>>>(Pr, wre, wim, C2);
  k_idft<<<1024, 256, 0, stream>>>(C2, out);
}

// Round 3
// 162.504 us; speedup vs baseline: 1.0404x; 1.0404x over previous
//
#include <hip/hip_runtime.h>
#include <cmath>

// Problem constants
#define BATCH 8
#define NH 8
#define SEQ 1024
#define DH 64          // head dim
#define NM 64          // modes

// ws layout (floats):
//  Pr2 : [th 2][inp 2][bh 64][c 2][m 64][d 64] = 2,097,152  (2 t-partials)
//  C2  : [bh 64][j 64][m 64][c 2]              =   524,288
//  C1c : [bh 64][i 64][q 64][c 2]              =   524,288
#define PLANE 4096     // 64m * 64d
#define C2_OFF (4 * 64 * 2 * PLANE)          // 2,097,152 floats
#define C1C_OFF (C2_OFF + 64 * 64 * 64 * 2)  // + 524,288

// ---------------------------------------------------------------------------
// Kernel 1: forward partial DFT with t<->t+512 symmetry, 2 t-partials only.
// grid = (bh 64, inp 2, dh 2, th 2) = 512 blocks x 512 thr.
// LDS 72 KB -> 2 blocks/CU = 16 waves/CU = 4 waves/SIMD.
// ---------------------------------------------------------------------------
__global__ __launch_bounds__(512, 4) void k_dft(const float* __restrict__ q,
                                                const float* __restrict__ k,
                                                float* __restrict__ Pr) {
  const int bid = blockIdx.x;
  const int bh = bid & 63;
  const int inp = (bid >> 6) & 1;
  const int dh = (bid >> 7) & 1;   // which 32-d half
  const int th = bid >> 8;         // which 256-t' half
  const float* x = (inp ? k : q) + (size_t)bh * (SEQ * DH);  // [t][d]

  __shared__ __align__(16) float se[256 * 36];  // row stride 36 (9 quads, odd)
  __shared__ __align__(16) float so[256 * 36];
  const int tid = threadIdx.x;
  const int dg  = tid & 3;         // 4 d-groups of 8 -> d0 in [0,32)
  const int par = (tid >> 2) & 3;  // 4-way t-interleave stream
  const int pg  = (tid >> 4) & 1;  // mode parity
  const int mgl = tid >> 5;        // 0..15 -> 2 modes each
  const int d0 = dg * 8;
  // modes handled: m = 4*mgl + 2*mi + pg, mi in {0,1}

  const int tb = th * 256;
  {
    const float4* xf = reinterpret_cast<const float4*>(x);
#pragma unroll
    for (int i = 0; i < 4; ++i) {
      int idx = tid + i * 512;          // 0..2047
      int tt = idx >> 3, f4 = idx & 7;  // t'-row, float4 within 32-float half
      size_t ga = (size_t)(tb + tt) * 16 + dh * 8 + f4;
      float4 a = xf[ga];
      float4 b = xf[ga + 512 * 16];
      *reinterpret_cast<float4*>(&se[tt * 36 + f4 * 4]) =
          make_float4(a.x + b.x, a.y + b.y, a.z + b.z, a.w + b.w);
      *reinterpret_cast<float4*>(&so[tt * 36 + f4 * 4]) =
          make_float4(a.x - b.x, a.y - b.y, a.z - b.z, a.w - b.w);
    }
  }
  __syncthreads();

  const float* s = pg ? so : se;

  float accr[2][8] = {{0.f}}, acci[2][8] = {{0.f}};
  float stepc[2], steps[2], wr[2], wi[2];
#pragma unroll
  for (int mi = 0; mi < 2; ++mi) {
    const int m = 4 * mgl + 2 * mi + pg;
    const int ps = (4 * m) & 1023;  // t' advances by 4
    stepc[mi] = cospif((float)ps * (1.0f / 512.0f));
    steps[mi] = -sinpif((float)ps * (1.0f / 512.0f));
    const int p0 = (m * (tb + par)) & 1023;
    wr[mi] = cospif((float)p0 * (1.0f / 512.0f));
    wi[mi] = -sinpif((float)p0 * (1.0f / 512.0f));
  }

#pragma unroll 4
  for (int k2 = 0; k2 < 64; ++k2) {
    const int tl = 4 * k2 + par;
    float4 a = *reinterpret_cast<const float4*>(&s[tl * 36 + d0]);
    float4 b = *reinterpret_cast<const float4*>(&s[tl * 36 + d0 + 4]);
    float xv[8] = {a.x, a.y, a.z, a.w, b.x, b.y, b.z, b.w};
#pragma unroll
    for (int mi = 0; mi < 2; ++mi) {
      float cwr = wr[mi], cwi = wi[mi];
#pragma unroll
      for (int di = 0; di < 8; ++di) {
        accr[mi][di] = fmaf(cwr, xv[di], accr[mi][di]);
        acci[mi][di] = fmaf(cwi, xv[di], acci[mi][di]);
      }
      float nr = cwr * stepc[mi] - cwi * steps[mi];
      float ni = cwr * steps[mi] + cwi * stepc[mi];
      wr[mi] = nr; wi[mi] = ni;
    }
  }

  // combine 4 par streams (partner lanes differ in bits 2,3)
#pragma unroll
  for (int mi = 0; mi < 2; ++mi) {
#pragma unroll
    for (int di = 0; di < 8; ++di) {
      accr[mi][di] += __shfl_xor(accr[mi][di], 4, 64);
      acci[mi][di] += __shfl_xor(acci[mi][di], 4, 64);
      accr[mi][di] += __shfl_xor(accr[mi][di], 8, 64);
      acci[mi][di] += __shfl_xor(acci[mi][di], 8, 64);
    }
  }

  if (par == 0) {
    const size_t base =
        (((size_t)th * 2 + inp) * 64 + bh) * (2 * PLANE) + dh * 32 + d0;
#pragma unroll
    for (int mi = 0; mi < 2; ++mi) {
      const int m = 4 * mgl + 2 * mi + pg;
      float* pr = Pr + base + (size_t)m * 64;
      float* pi = pr + PLANE;
      *reinterpret_cast<float4*>(pr) =
          make_float4(accr[mi][0], accr[mi][1], accr[mi][2], accr[mi][3]);
      *reinterpret_cast<float4*>(pr + 4) =
          make_float4(accr[mi][4], accr[mi][5], accr[mi][6], accr[mi][7]);
      *reinterpret_cast<float4*>(pi) =
          make_float4(acci[mi][0], acci[mi][1], acci[mi][2], acci[mi][3]);
      *reinterpret_cast<float4*>(pi + 4) =
          make_float4(acci[mi][4], acci[mi][5], acci[mi][6], acci[mi][7]);
    }
  }
}

// stable complex tanh
__device__ __forceinline__ void ctanh_f(float x, float y, float& rr, float& ri) {
  float a = 2.0f * x, b = 2.0f * y;
  if (fabsf(a) > 20.0f) {
    rr = (a > 0.0f) ? 1.0f : -1.0f;
    ri = 0.0f;
  } else {
    float ea = expf(a), ena = expf(-a);
    float sb, cb;
    sincosf(b, &sb, &cb);
    float den = 0.5f * (ea + ena) + cb;
    rr = 0.5f * (ea - ena) / den;
    ri = sb / den;
  }
}

// ---------------------------------------------------------------------------
// Kernel 2: scores -> ctanh -> context -> C1c. grid = (bh, q-eighth) = 512
// blocks x 512 thr, ~48 KB LDS -> 3 blocks/CU. Sums the 2 Pr t-partials
// during staging. Weight contraction moved OUT (k_w) because the fused
// version's 8-q blocks fetched weights at 32B/128B-line = 88 MB from HBM.
// ---------------------------------------------------------------------------
__global__ __launch_bounds__(512) void k_ctx(const float* __restrict__ Pr,
                                             float* __restrict__ C1c) {
  __shared__ float Kr[64][68], Ki[64][68];
  __shared__ float Qr[8][68], Qi[8][68];
  __shared__ float Ar[8][68], Ai[8][68];
  __shared__ float C1rs[64][9], C1is[64][9];

  const int tid = threadIdx.x;
  const int bh = blockIdx.x >> 3;
  const int qo = blockIdx.x & 7;  // 8 q's per block

  const float4* pf = reinterpret_cast<const float4*>(Pr);
  const size_t TH4 = (size_t)2 * 64 * 2 * 1024;  // th stride in float4 = 262144

  // K: Pr[th][inp=1][bh][c][m][d], sum th partials
  const float4* k0 = pf + (size_t)(64 + bh) * 2048;
  const float4* k1 = k0 + TH4;
  for (int idx = tid; idx < 1024; idx += 512) {
    int kk = idx >> 4, dd = (idx & 15) * 4;
    float4 r0 = k0[idx], r1 = k1[idx];
    float4 i0 = k0[idx + 1024], i1 = k1[idx + 1024];
    *reinterpret_cast<float4*>(&Kr[kk][dd]) =
        make_float4(r0.x + r1.x, r0.y + r1.y, r0.z + r1.z, r0.w + r1.w);
    *reinterpret_cast<float4*>(&Ki[kk][dd]) =
        make_float4(i0.x + i1.x, i0.y + i1.y, i0.z + i1.z, i0.w + i1.w);
  }
  // Q: Pr[th][inp=0][bh][c][qo*8 .. qo*8+7][d], sum th partials
  {
    const float4* q0 = pf + (size_t)bh * 2048 + qo * 128;
    const float4* q1 = q0 + TH4;
    if (tid < 128) {
      int qi2 = tid >> 4, dd = (tid & 15) * 4;
      float4 r0 = q0[tid], r1 = q1[tid];
      float4 i0 = q0[tid + 1024], i1 = q1[tid + 1024];
      *reinterpret_cast<float4*>(&Qr[qi2][dd]) =
          make_float4(r0.x + r1.x, r0.y + r1.y, r0.z + r1.z, r0.w + r1.w);
      *reinterpret_cast<float4*>(&Qi[qi2][dd]) =
          make_float4(i0.x + i1.x, i0.y + i1.y, i0.z + i1.z, i0.w + i1.w);
    }
  }
  __syncthreads();

  // scores S[q][k] = sum_d Q[q][d]*K[k][d] (complex, no conj) -> ctanh
  {
    const int qq = tid >> 6, kk = tid & 63;
    float s0 = 0.f, s1 = 0.f;
    for (int d = 0; d < 64; d += 4) {
      const float4 qr = *reinterpret_cast<const float4*>(&Qr[qq][d]);
      const float4 qi = *reinterpret_cast<const float4*>(&Qi[qq][d]);
      const float4 kr = *reinterpret_cast<const float4*>(&Kr[kk][d]);
      const float4 ki = *reinterpret_cast<const float4*>(&Ki[kk][d]);
      s0 = fmaf(qr.x, kr.x, s0); s0 = fmaf(-qi.x, ki.x, s0);
      s1 = fmaf(qr.x, ki.x, s1); s1 = fmaf(qi.x, kr.x, s1);
      s0 = fmaf(qr.y, kr.y, s0); s0 = fmaf(-qi.y, ki.y, s0);
      s1 = fmaf(qr.y, ki.y, s1); s1 = fmaf(qi.y, kr.y, s1);
      s0 = fmaf(qr.z, kr.z, s0); s0 = fmaf(-qi.z, ki.z, s0);
      s1 = fmaf(qr.z, ki.z, s1); s1 = fmaf(qi.z, kr.z, s1);
      s0 = fmaf(qr.w, kr.w, s0); s0 = fmaf(-qi.w, ki.w, s0);
      s1 = fmaf(qr.w, ki.w, s1); s1 = fmaf(qi.w, kr.w, s1);
    }
    float rr, ri;
    ctanh_f(s0, s1, rr, ri);
    Ar[qq][kk] = rr;
    Ai[qq][kk] = ri;
  }
  __syncthreads();

  // C1[d][q] = sum_k A[q][k]*K[k][d]; thread (q, d) -> lane-consecutive K
  {
    const int qq = tid >> 6, dd = tid & 63;
    float cr = 0.f, ci = 0.f;
#pragma unroll 8
    for (int kk = 0; kk < 64; ++kk) {
      float a_r = Ar[qq][kk], a_i = Ai[qq][kk];  // broadcast
      float krv = Kr[kk][dd], kiv = Ki[kk][dd];
      cr = fmaf(a_r, krv, cr); cr = fmaf(-a_i, kiv, cr);
      ci = fmaf(a_r, kiv, ci); ci = fmaf(a_i, krv, ci);
    }
    C1rs[dd][qq] = cr;
    C1is[dd][qq] = ci;
  }
  __syncthreads();

  // write C1c[bh][i][qglobal][2]: 64i x 8q = 512 cells, one per thread
  {
    const int i = tid >> 3, ql = tid & 7;
    size_t o = (((size_t)bh * 64 + i) * 64 + qo * 8 + ql) * 2;
    *reinterpret_cast<float2*>(&C1c[o]) = make_float2(C1rs[i][ql], C1is[i][ql]);
  }
}

// ---------------------------------------------------------------------------
// Kernel 2b: C2[b,h,j,q] = sum_i C1[b,h,i,q] * w[h,i,j,q].
// grid = (h 8, j 64) = 512 blocks x 512 thr (b = tid>>6, q = tid&63).
// Weight rows w[h][:][j][:] staged ONCE per block in LDS (32 KB, coalesced
// 256B rows) -> weight HBM traffic = 16.8 MB minimum (was 88 MB fused).
// C1 reads: 512B/wave coalesced, L2-resident (4.2 MB tensor, 64x j-reuse).
// ---------------------------------------------------------------------------
__global__ __launch_bounds__(512) void k_w(const float* __restrict__ C1c,
                                           const float* __restrict__ wre,
                                           const float* __restrict__ wim,
                                           float* __restrict__ C2) {
  __shared__ float Wr[64][64], Wi[64][64];  // [i][q]
  const int tid = threadIdx.x;
  const int j = blockIdx.x & 63;
  const int h = blockIdx.x >> 6;

  // stage weights: w[h][i][j][q], i = idx>>6, q = idx&63 -> 256B per row
  {
    const size_t wbase = (size_t)h * 262144 + (size_t)j * 64;
#pragma unroll
    for (int p = 0; p < 8; ++p) {
      int idx = tid + p * 512;
      int i = idx >> 6, qq = idx & 63;
      Wr[i][qq] = wre[wbase + (size_t)i * 4096 + qq];
      Wi[i][qq] = wim[wbase + (size_t)i * 4096 + qq];
    }
  }
  __syncthreads();

  const int b = tid >> 6, qq = tid & 63;
  const int bh = b * 8 + h;
  const float2* c1 = reinterpret_cast<const float2*>(C1c) + (size_t)bh * 4096 + qq;

  float ar = 0.f, ai = 0.f;
#pragma unroll 8
  for (int i = 0; i < 64; ++i) {
    float2 c = c1[(size_t)i * 64];
    float wr = Wr[i][qq], wi = Wi[i][qq];
    ar = fmaf(c.x, wr, ar); ar = fmaf(-c.y, wi, ar);
    ai = fmaf(c.x, wi, ai); ai = fmaf(c.y, wr, ai);
  }
  *reinterpret_cast<float2*>(&C2[(((size_t)bh * 64 + j) * 64 + qq) * 2]) =
      make_float2(ar, ai);
}

// ---------------------------------------------------------------------------
// Kernel 3 (unchanged, control): inverse partial DFT with (-1)^m symmetry.
// grid = (bh 64, tc 8, jh 2) = 1024 blocks x 256 thr. LDS 18.4 KB.
// ---------------------------------------------------------------------------
__global__ __launch_bounds__(256) void k_idft(const float* __restrict__ C2,
                                              float* __restrict__ out) {
  __shared__ float Cr[64][36], Ci[64][36];
  const int tid = threadIdx.x;
  const int jh = blockIdx.x & 1;
  const int tc = (blockIdx.x >> 1) & 7;
  const int bh = blockIdx.x >> 4;
  const float s = 1.0f / (512.0f * 512.0f * 1024.0f);

  // stage 64 m x 32 j (this block's j-half), scale pre-folded
  for (int idx = tid; idx < 2048; idx += 256) {
    int j = idx >> 6, m = idx & 63;  // j 0..31 local
    int jg_ = jh * 32 + j;
    float f = (m == 0) ? s : 2.0f * s;
    float2 c = *reinterpret_cast<const float2*>(&C2[(((size_t)bh * 64 + jg_) * 64 + m) * 2]);
    Cr[m][j] = f * c.x;
    Ci[m][j] = f * c.y;
  }
  __syncthreads();

  const int tg = tid & 15, jg = tid >> 4;  // tg 16 x 4t', jg 16 x 2j
  const int tp0 = tc * 64 + tg * 4;        // 4 consecutive t'
  const int j0 = jg * 2;                   // 2 consecutive j (local)

  float sc[4], ss[4], wc[4], wsn[4];
#pragma unroll
  for (int kk = 0; kk < 4; ++kk) {
    float ph = (float)((tp0 + kk) & 1023) * (1.0f / 512.0f);
    sc[kk] = cospif(ph);  // step e^{+2*pi*i*t'/1024} per m
    ss[kk] = sinpif(ph);
    wc[kk] = 1.0f;        // m = 0
    wsn[kk] = 0.0f;
  }

  float accE[4][2] = {{0.f}}, accO[4][2] = {{0.f}};
#pragma unroll 4
  for (int m = 0; m < 64; ++m) {
    float2 c0 = *reinterpret_cast<const float2*>(&Cr[m][j0]);
    float2 e0 = *reinterpret_cast<const float2*>(&Ci[m][j0]);
    float crv[2] = {c0.x, c0.y};
    float civ[2] = {e0.x, e0.y};
    float(*acc)[2] = (m & 1) ? accO : accE;
#pragma unroll
    for (int kk = 0; kk < 4; ++kk) {
      float cw = wc[kk], sw = wsn[kk];
#pragma unroll
      for (int jj = 0; jj < 2; ++jj) {
        acc[kk][jj] = fmaf(crv[jj], cw, acc[kk][jj]);
        acc[kk][jj] = fmaf(-civ[jj], sw, acc[kk][jj]);
      }
      float nr = cw * sc[kk] - sw * ss[kk];
      float ni = cw * ss[kk] + sw * sc[kk];
      wc[kk] = nr; wsn[kk] = ni;
    }
  }

  // out[bh][j][t]: float4 at tp0 (E+O) and float4 at tp0+512 (E-O)
#pragma unroll
  for (int jj = 0; jj < 2; ++jj) {
    float* row = &out[((size_t)bh * 64 + jh * 32 + j0 + jj) * 1024];
    *reinterpret_cast<float4*>(&row[tp0]) =
        make_float4(accE[0][jj] + accO[0][jj], accE[1][jj] + accO[1][jj],
                    accE[2][jj] + accO[2][jj], accE[3][jj] + accO[3][jj]);
    *reinterpret_cast<float4*>(&row[tp0 + 512]) =
        make_float4(accE[0][jj] - accO[0][jj], accE[1][jj] - accO[1][jj],
                    accE[2][jj] - accO[2][jj], accE[3][jj] - accO[3][jj]);
  }
}

extern "C" void kernel_launch(void* const* d_in, const int* in_sizes, int n_in,
                              void* d_out, int out_size, void* d_ws, size_t ws_size,
                              hipStream_t stream) {
  const float* q   = (const float*)d_in[0];
  const float* k   = (const float*)d_in[1];
  // d_in[2] = value, unused by the reference forward
  const float* wre = (const float*)d_in[3];
  const float* wim = (const float*)d_in[4];
  float* out = (float*)d_out;
  float* ws  = (float*)d_ws;

  float* Pr  = ws;
  float* C2  = ws + C2_OFF;
  float* C1c = ws + C1C_OFF;

  k_dft <<<512, 512, 0, stream>>>(q, k, Pr);
  k_ctx <<<512, 512, 0, stream>>>(Pr, C1c);
  k_w   <<<512, 512, 0, stream>>>(C1c, wre, wim, C2);
  k_idft<<<1024, 256, 0, stream>>>(C2, out);
}

// Round 4
// 147.516 us; speedup vs baseline: 1.1461x; 1.1016x over previous
//
#include <hip/hip_runtime.h>
#include <cmath>

// Problem constants
#define BATCH 8
#define NH 8
#define SEQ 1024
#define DH 64          // head dim
#define NM 64          // modes

// ws layout (floats):
//  Pr2 : [th 2][inp 2][bh 64][c 2][m 64][d 64] = 2,097,152  (2 t-partials)
//  C2  : [bh 64][j 64][m 64][c 2]              =   524,288
//  C1c : [bh 64][i 64][q 64][c 2]              =   524,288
#define PLANE 4096     // 64m * 64d
#define C2_OFF (4 * 64 * 2 * PLANE)          // 2,097,152 floats
#define C1C_OFF (C2_OFF + 64 * 64 * 64 * 2)  // + 524,288

// ---------------------------------------------------------------------------
// Kernel 1 (control, unchanged): forward partial DFT, t<->t+512 symmetry.
// grid = (bh 64, inp 2, dh 2, th 2) = 512 blocks x 512 thr. LDS 72 KB.
// ---------------------------------------------------------------------------
__global__ __launch_bounds__(512, 4) void k_dft(const float* __restrict__ q,
                                                const float* __restrict__ k,
                                                float* __restrict__ Pr) {
  const int bid = blockIdx.x;
  const int bh = bid & 63;
  const int inp = (bid >> 6) & 1;
  const int dh = (bid >> 7) & 1;   // which 32-d half
  const int th = bid >> 8;         // which 256-t' half
  const float* x = (inp ? k : q) + (size_t)bh * (SEQ * DH);  // [t][d]

  __shared__ __align__(16) float se[256 * 36];  // row stride 36 (9 quads, odd)
  __shared__ __align__(16) float so[256 * 36];
  const int tid = threadIdx.x;
  const int dg  = tid & 3;         // 4 d-groups of 8 -> d0 in [0,32)
  const int par = (tid >> 2) & 3;  // 4-way t-interleave stream
  const int pg  = (tid >> 4) & 1;  // mode parity
  const int mgl = tid >> 5;        // 0..15 -> 2 modes each
  const int d0 = dg * 8;
  // modes handled: m = 4*mgl + 2*mi + pg, mi in {0,1}

  const int tb = th * 256;
  {
    const float4* xf = reinterpret_cast<const float4*>(x);
#pragma unroll
    for (int i = 0; i < 4; ++i) {
      int idx = tid + i * 512;          // 0..2047
      int tt = idx >> 3, f4 = idx & 7;  // t'-row, float4 within 32-float half
      size_t ga = (size_t)(tb + tt) * 16 + dh * 8 + f4;
      float4 a = xf[ga];
      float4 b = xf[ga + 512 * 16];
      *reinterpret_cast<float4*>(&se[tt * 36 + f4 * 4]) =
          make_float4(a.x + b.x, a.y + b.y, a.z + b.z, a.w + b.w);
      *reinterpret_cast<float4*>(&so[tt * 36 + f4 * 4]) =
          make_float4(a.x - b.x, a.y - b.y, a.z - b.z, a.w - b.w);
    }
  }
  __syncthreads();

  const float* s = pg ? so : se;

  float accr[2][8] = {{0.f}}, acci[2][8] = {{0.f}};
  float stepc[2], steps[2], wr[2], wi[2];
#pragma unroll
  for (int mi = 0; mi < 2; ++mi) {
    const int m = 4 * mgl + 2 * mi + pg;
    const int ps = (4 * m) & 1023;  // t' advances by 4
    stepc[mi] = cospif((float)ps * (1.0f / 512.0f));
    steps[mi] = -sinpif((float)ps * (1.0f / 512.0f));
    const int p0 = (m * (tb + par)) & 1023;
    wr[mi] = cospif((float)p0 * (1.0f / 512.0f));
    wi[mi] = -sinpif((float)p0 * (1.0f / 512.0f));
  }

#pragma unroll 4
  for (int k2 = 0; k2 < 64; ++k2) {
    const int tl = 4 * k2 + par;
    float4 a = *reinterpret_cast<const float4*>(&s[tl * 36 + d0]);
    float4 b = *reinterpret_cast<const float4*>(&s[tl * 36 + d0 + 4]);
    float xv[8] = {a.x, a.y, a.z, a.w, b.x, b.y, b.z, b.w};
#pragma unroll
    for (int mi = 0; mi < 2; ++mi) {
      float cwr = wr[mi], cwi = wi[mi];
#pragma unroll
      for (int di = 0; di < 8; ++di) {
        accr[mi][di] = fmaf(cwr, xv[di], accr[mi][di]);
        acci[mi][di] = fmaf(cwi, xv[di], acci[mi][di]);
      }
      float nr = cwr * stepc[mi] - cwi * steps[mi];
      float ni = cwr * steps[mi] + cwi * stepc[mi];
      wr[mi] = nr; wi[mi] = ni;
    }
  }

  // combine 4 par streams (partner lanes differ in bits 2,3)
#pragma unroll
  for (int mi = 0; mi < 2; ++mi) {
#pragma unroll
    for (int di = 0; di < 8; ++di) {
      accr[mi][di] += __shfl_xor(accr[mi][di], 4, 64);
      acci[mi][di] += __shfl_xor(acci[mi][di], 4, 64);
      accr[mi][di] += __shfl_xor(accr[mi][di], 8, 64);
      acci[mi][di] += __shfl_xor(acci[mi][di], 8, 64);
    }
  }

  if (par == 0) {
    const size_t base =
        (((size_t)th * 2 + inp) * 64 + bh) * (2 * PLANE) + dh * 32 + d0;
#pragma unroll
    for (int mi = 0; mi < 2; ++mi) {
      const int m = 4 * mgl + 2 * mi + pg;
      float* pr = Pr + base + (size_t)m * 64;
      float* pi = pr + PLANE;
      *reinterpret_cast<float4*>(pr) =
          make_float4(accr[mi][0], accr[mi][1], accr[mi][2], accr[mi][3]);
      *reinterpret_cast<float4*>(pr + 4) =
          make_float4(accr[mi][4], accr[mi][5], accr[mi][6], accr[mi][7]);
      *reinterpret_cast<float4*>(pi) =
          make_float4(acci[mi][0], acci[mi][1], acci[mi][2], acci[mi][3]);
      *reinterpret_cast<float4*>(pi + 4) =
          make_float4(acci[mi][4], acci[mi][5], acci[mi][6], acci[mi][7]);
    }
  }
}

// stable complex tanh
__device__ __forceinline__ void ctanh_f(float x, float y, float& rr, float& ri) {
  float a = 2.0f * x, b = 2.0f * y;
  if (fabsf(a) > 20.0f) {
    rr = (a > 0.0f) ? 1.0f : -1.0f;
    ri = 0.0f;
  } else {
    float ea = expf(a), ena = expf(-a);
    float sb, cb;
    sincosf(b, &sb, &cb);
    float den = 0.5f * (ea + ena) + cb;
    rr = 0.5f * (ea - ena) / den;
    ri = sb / den;
  }
}

// ---------------------------------------------------------------------------
// Kernel 2: scores -> ctanh -> context -> C1c. 512 blocks x 512 thr.
// XCD swizzle: bh = bid&63, qo = bid>>6 -> the 8 qo-siblings sharing one
// bh's K-tile are 64 apart (== same bid%8 -> same XCD L2). Old decode put
// them on 8 DIFFERENT XCDs -> 8x K re-fetch (~35 MB of k_mid's 88 MB).
// ---------------------------------------------------------------------------
__global__ __launch_bounds__(512) void k_ctx(const float* __restrict__ Pr,
                                             float* __restrict__ C1c) {
  __shared__ float Kr[64][68], Ki[64][68];
  __shared__ float Qr[8][68], Qi[8][68];
  __shared__ float Ar[8][68], Ai[8][68];
  __shared__ float C1rs[64][9], C1is[64][9];

  const int tid = threadIdx.x;
  const int bh = blockIdx.x & 63;   // XCD-swizzled decode
  const int qo = blockIdx.x >> 6;   // 8 q's per block

  const float4* pf = reinterpret_cast<const float4*>(Pr);
  const size_t TH4 = (size_t)2 * 64 * 2 * 1024;  // th stride in float4 = 262144

  // K: Pr[th][inp=1][bh][c][m][d], sum th partials
  const float4* k0 = pf + (size_t)(64 + bh) * 2048;
  const float4* k1 = k0 + TH4;
  for (int idx = tid; idx < 1024; idx += 512) {
    int kk = idx >> 4, dd = (idx & 15) * 4;
    float4 r0 = k0[idx], r1 = k1[idx];
    float4 i0 = k0[idx + 1024], i1 = k1[idx + 1024];
    *reinterpret_cast<float4*>(&Kr[kk][dd]) =
        make_float4(r0.x + r1.x, r0.y + r1.y, r0.z + r1.z, r0.w + r1.w);
    *reinterpret_cast<float4*>(&Ki[kk][dd]) =
        make_float4(i0.x + i1.x, i0.y + i1.y, i0.z + i1.z, i0.w + i1.w);
  }
  // Q: Pr[th][inp=0][bh][c][qo*8 .. qo*8+7][d], sum th partials
  {
    const float4* q0 = pf + (size_t)bh * 2048 + qo * 128;
    const float4* q1 = q0 + TH4;
    if (tid < 128) {
      int qi2 = tid >> 4, dd = (tid & 15) * 4;
      float4 r0 = q0[tid], r1 = q1[tid];
      float4 i0 = q0[tid + 1024], i1 = q1[tid + 1024];
      *reinterpret_cast<float4*>(&Qr[qi2][dd]) =
          make_float4(r0.x + r1.x, r0.y + r1.y, r0.z + r1.z, r0.w + r1.w);
      *reinterpret_cast<float4*>(&Qi[qi2][dd]) =
          make_float4(i0.x + i1.x, i0.y + i1.y, i0.z + i1.z, i0.w + i1.w);
    }
  }
  __syncthreads();

  // scores S[q][k] = sum_d Q[q][d]*K[k][d] (complex, no conj) -> ctanh
  {
    const int qq = tid >> 6, kk = tid & 63;
    float s0 = 0.f, s1 = 0.f;
    for (int d = 0; d < 64; d += 4) {
      const float4 qr = *reinterpret_cast<const float4*>(&Qr[qq][d]);
      const float4 qi = *reinterpret_cast<const float4*>(&Qi[qq][d]);
      const float4 kr = *reinterpret_cast<const float4*>(&Kr[kk][d]);
      const float4 ki = *reinterpret_cast<const float4*>(&Ki[kk][d]);
      s0 = fmaf(qr.x, kr.x, s0); s0 = fmaf(-qi.x, ki.x, s0);
      s1 = fmaf(qr.x, ki.x, s1); s1 = fmaf(qi.x, kr.x, s1);
      s0 = fmaf(qr.y, kr.y, s0); s0 = fmaf(-qi.y, ki.y, s0);
      s1 = fmaf(qr.y, ki.y, s1); s1 = fmaf(qi.y, kr.y, s1);
      s0 = fmaf(qr.z, kr.z, s0); s0 = fmaf(-qi.z, ki.z, s0);
      s1 = fmaf(qr.z, ki.z, s1); s1 = fmaf(qi.z, kr.z, s1);
      s0 = fmaf(qr.w, kr.w, s0); s0 = fmaf(-qi.w, ki.w, s0);
      s1 = fmaf(qr.w, ki.w, s1); s1 = fmaf(qi.w, kr.w, s1);
    }
    float rr, ri;
    ctanh_f(s0, s1, rr, ri);
    Ar[qq][kk] = rr;
    Ai[qq][kk] = ri;
  }
  __syncthreads();

  // C1[d][q] = sum_k A[q][k]*K[k][d]; thread (q, d) -> lane-consecutive K
  {
    const int qq = tid >> 6, dd = tid & 63;
    float cr = 0.f, ci = 0.f;
#pragma unroll 8
    for (int kk = 0; kk < 64; ++kk) {
      float a_r = Ar[qq][kk], a_i = Ai[qq][kk];  // broadcast
      float krv = Kr[kk][dd], kiv = Ki[kk][dd];
      cr = fmaf(a_r, krv, cr); cr = fmaf(-a_i, kiv, cr);
      ci = fmaf(a_r, kiv, ci); ci = fmaf(a_i, krv, ci);
    }
    C1rs[dd][qq] = cr;
    C1is[dd][qq] = ci;
  }
  __syncthreads();

  // write C1c[bh][i][qglobal][2]: 64i x 8q = 512 cells, one per thread
  {
    const int i = tid >> 3, ql = tid & 7;
    size_t o = (((size_t)bh * 64 + i) * 64 + qo * 8 + ql) * 2;
    *reinterpret_cast<float2*>(&C1c[o]) = make_float2(C1rs[i][ql], C1is[i][ql]);
  }
}

// ---------------------------------------------------------------------------
// Kernel 2b: C2[b,h,j,q] = sum_i C1[b,h,i,q] * w[h,i,j,q].
// 512 blocks x 512 thr. XCD swizzle: h = bid&7, j = bid>>3 -> the 64
// j-siblings sharing an h's C1 slice (524 KB < 4 MB L2) are 8 apart ->
// same XCD. Weight staging unchanged (each weight read exactly once).
// ---------------------------------------------------------------------------
__global__ __launch_bounds__(512) void k_w(const float* __restrict__ C1c,
                                           const float* __restrict__ wre,
                                           const float* __restrict__ wim,
                                           float* __restrict__ C2) {
  __shared__ float Wr[64][64], Wi[64][64];  // [i][q]
  const int tid = threadIdx.x;
  const int h = blockIdx.x & 7;    // XCD-swizzled decode
  const int j = blockIdx.x >> 3;

  // stage weights: w[h][i][j][q], i = idx>>6, q = idx&63 -> 256B per row
  {
    const size_t wbase = (size_t)h * 262144 + (size_t)j * 64;
#pragma unroll
    for (int p = 0; p < 8; ++p) {
      int idx = tid + p * 512;
      int i = idx >> 6, qq = idx & 63;
      Wr[i][qq] = wre[wbase + (size_t)i * 4096 + qq];
      Wi[i][qq] = wim[wbase + (size_t)i * 4096 + qq];
    }
  }
  __syncthreads();

  const int b = tid >> 6, qq = tid & 63;
  const int bh = b * 8 + h;
  const float2* c1 = reinterpret_cast<const float2*>(C1c) + (size_t)bh * 4096 + qq;

  float ar = 0.f, ai = 0.f;
#pragma unroll 8
  for (int i = 0; i < 64; ++i) {
    float2 c = c1[(size_t)i * 64];
    float wr = Wr[i][qq], wi = Wi[i][qq];
    ar = fmaf(c.x, wr, ar); ar = fmaf(-c.y, wi, ar);
    ai = fmaf(c.x, wi, ai); ai = fmaf(c.y, wr, ai);
  }
  *reinterpret_cast<float2*>(&C2[(((size_t)bh * 64 + j) * 64 + qq) * 2]) =
      make_float2(ar, ai);
}

// ---------------------------------------------------------------------------
// Kernel 3: inverse partial DFT with (-1)^m symmetry. 1024 blocks x 256 thr.
// XCD swizzle: tc = bid>>7, (bh,jh) = low 7 bits -> the 8 tc-siblings
// sharing one (bh,jh) C2 tile are 128 apart -> same XCD.
// ---------------------------------------------------------------------------
__global__ __launch_bounds__(256) void k_idft(const float* __restrict__ C2,
                                              float* __restrict__ out) {
  __shared__ float Cr[64][36], Ci[64][36];
  const int tid = threadIdx.x;
  const int low = blockIdx.x & 127;  // XCD-swizzled decode
  const int jh = low & 1;
  const int bh = low >> 1;
  const int tc = blockIdx.x >> 7;
  const float s = 1.0f / (512.0f * 512.0f * 1024.0f);

  // stage 64 m x 32 j (this block's j-half), scale pre-folded
  for (int idx = tid; idx < 2048; idx += 256) {
    int j = idx >> 6, m = idx & 63;  // j 0..31 local
    int jg_ = jh * 32 + j;
    float f = (m == 0) ? s : 2.0f * s;
    float2 c = *reinterpret_cast<const float2*>(&C2[(((size_t)bh * 64 + jg_) * 64 + m) * 2]);
    Cr[m][j] = f * c.x;
    Ci[m][j] = f * c.y;
  }
  __syncthreads();

  const int tg = tid & 15, jg = tid >> 4;  // tg 16 x 4t', jg 16 x 2j
  const int tp0 = tc * 64 + tg * 4;        // 4 consecutive t'
  const int j0 = jg * 2;                   // 2 consecutive j (local)

  float sc[4], ss[4], wc[4], wsn[4];
#pragma unroll
  for (int kk = 0; kk < 4; ++kk) {
    float ph = (float)((tp0 + kk) & 1023) * (1.0f / 512.0f);
    sc[kk] = cospif(ph);  // step e^{+2*pi*i*t'/1024} per m
    ss[kk] = sinpif(ph);
    wc[kk] = 1.0f;        // m = 0
    wsn[kk] = 0.0f;
  }

  float accE[4][2] = {{0.f}}, accO[4][2] = {{0.f}};
#pragma unroll 4
  for (int m = 0; m < 64; ++m) {
    float2 c0 = *reinterpret_cast<const float2*>(&Cr[m][j0]);
    float2 e0 = *reinterpret_cast<const float2*>(&Ci[m][j0]);
    float crv[2] = {c0.x, c0.y};
    float civ[2] = {e0.x, e0.y};
    float(*acc)[2] = (m & 1) ? accO : accE;
#pragma unroll
    for (int kk = 0; kk < 4; ++kk) {
      float cw = wc[kk], sw = wsn[kk];
#pragma unroll
      for (int jj = 0; jj < 2; ++jj) {
        acc[kk][jj] = fmaf(crv[jj], cw, acc[kk][jj]);
        acc[kk][jj] = fmaf(-civ[jj], sw, acc[kk][jj]);
      }
      float nr = cw * sc[kk] - sw * ss[kk];
      float ni = cw * ss[kk] + sw * sc[kk];
      wc[kk] = nr; wsn[kk] = ni;
    }
  }

  // out[bh][j][t]: float4 at tp0 (E+O) and float4 at tp0+512 (E-O)
#pragma unroll
  for (int jj = 0; jj < 2; ++jj) {
    float* row = &out[((size_t)bh * 64 + jh * 32 + j0 + jj) * 1024];
    *reinterpret_cast<float4*>(&row[tp0]) =
        make_float4(accE[0][jj] + accO[0][jj], accE[1][jj] + accO[1][jj],
                    accE[2][jj] + accO[2][jj], accE[3][jj] + accO[3][jj]);
    *reinterpret_cast<float4*>(&row[tp0 + 512]) =
        make_float4(accE[0][jj] - accO[0][jj], accE[1][jj] - accO[1][jj],
                    accE[2][jj] - accO[2][jj], accE[3][jj] - accO[3][jj]);
  }
}

extern "C" void kernel_launch(void* const* d_in, const int* in_sizes, int n_in,
                              void* d_out, int out_size, void* d_ws, size_t ws_size,
                              hipStream_t stream) {
  const float* q   = (const float*)d_in[0];
  const float* k   = (const float*)d_in[1];
  // d_in[2] = value, unused by the reference forward
  const float* wre = (const float*)d_in[3];
  const float* wim = (const float*)d_in[4];
  float* out = (float*)d_out;
  float* ws  = (float*)d_ws;

  float* Pr  = ws;
  float* C2  = ws + C2_OFF;
  float* C1c = ws + C1C_OFF;

  k_dft <<<512, 512, 0, stream>>>(q, k, Pr);
  k_ctx <<<512, 512, 0, stream>>>(Pr, C1c);
  k_w   <<<512, 512, 0, stream>>>(C1c, wre, wim, C2);
  k_idft<<<1024, 256, 0, stream>>>(C2, out);
}